// Round 8
// baseline (1234.038 us; speedup 1.0000x reference)
//
#include <hip/hip_runtime.h>

// NCA with hypernetwork, MI355X bf16-MFMA implementation (round 5 kernel,
// third resubmit — rounds 5-7 all failed on GPU acquisition; never measured).
//
// Layouts (all in d_ws, rebuilt every call since ws is poisoned):
//   grid0/grid1/u : bf16, channels-last [s][y][x][ci], per-(y,x) 128B "ci-line",
//                   byte-swizzled  byte ^= ((x&7)<<4)   (bank-conflict-free ds_read_b128)
//   Wbuf          : bf16, [s][conv][tap][co][ci], per-co 128B ci-line,
//                   byte-swizzled  byte ^= ((co&7)<<4)
//
// Round-5 changes:
//   * wgen: 4-deep register pipeline (2-deep covered only 256cy of the ~900cy
//     HBM latency -> 650cy exposed stall per group; 60us, VALUBusy 20%).
//     Now 24 loads in flight, issued 3 compute-phases (~768cy) ahead of use.
//   * conv: ping-pong register prefetch across taps — issue tap t+1's 16
//     ds_read_b128 BEFORE tap t's 32 MFMAs (1 block/CU = 2 waves/SIMD can't
//     hide the serial read->MFMA chain by TLP alone). + setprio around MFMA.

typedef __attribute__((ext_vector_type(8))) short short8;     // 8 bf16 = 4 VGPR (MFMA frag)
typedef __attribute__((ext_vector_type(4))) float f32x4;      // MFMA acc frag
typedef __attribute__((ext_vector_type(8))) unsigned short us8;

__device__ __forceinline__ unsigned short f2bf(float f) {     // RNE f32->bf16
  unsigned int u = __builtin_bit_cast(unsigned int, f);
  u = (u + 0x7FFFu + ((u >> 16) & 1u)) >> 16;
  return (unsigned short)u;
}
__device__ __forceinline__ float bf2f(unsigned short h) {
  unsigned int u = ((unsigned int)h) << 16;
  return __builtin_bit_cast(float, u);
}

__device__ __forceinline__ void gl_lds16(const void* g, void* l) {
  // 16B-wide async global->LDS; LDS dest is wave-uniform base + lane*16 (m104).
  __builtin_amdgcn_global_load_lds((const __attribute__((address_space(1))) void*)g,
                                   (__attribute__((address_space(3))) void*)l, 16, 0, 0);
}

// ---------------- hypernet trunk: cond -> h1 -> h2 (store h2 transposed [k][s]) --------
__global__ void hyper_kernel(const int* __restrict__ labels, const float* __restrict__ emb,
                             const float* __restrict__ hw1, const float* __restrict__ hb1,
                             const float* __restrict__ hw2, const float* __restrict__ hb2,
                             float* __restrict__ h2T) {
  __shared__ float cond[128];
  __shared__ float h1[256];
  const int s = blockIdx.x, j = threadIdx.x;        // 32 blocks x 256 threads
  if (j < 128) cond[j] = emb[(size_t)labels[s] * 128 + j];
  __syncthreads();
  float a = hb1[j];
  for (int k = 0; k < 128; ++k) a += cond[k] * hw1[k * 256 + j];
  h1[j] = fmaxf(a, 0.f);
  __syncthreads();
  float a2 = hb2[j];
  for (int k = 0; k < 256; ++k) a2 += h1[k] * hw2[k * 256 + j];
  h2T[j * 32 + s] = fmaxf(a2, 0.f);                 // [256][32]
}

// ---------------- FiLM params: film[4][32][64] = g1,be1,g2,be2 -------------------------
__global__ void film_kernel(const int* __restrict__ labels, const float* __restrict__ emb,
                            const float* __restrict__ f1w1, const float* __restrict__ f1b1,
                            const float* __restrict__ f1w2, const float* __restrict__ f1b2,
                            const float* __restrict__ f2w1, const float* __restrict__ f2b1,
                            const float* __restrict__ f2w2, const float* __restrict__ f2b2,
                            float* __restrict__ film) {
  __shared__ float cond[128];
  __shared__ float hid[128];
  const int s = blockIdx.x, which = blockIdx.y, j = threadIdx.x;   // (32,2) x 128
  const float* W1 = which ? f2w1 : f1w1;
  const float* B1 = which ? f2b1 : f1b1;
  const float* W2 = which ? f2w2 : f1w2;
  const float* B2 = which ? f2b2 : f1b2;
  cond[j] = emb[(size_t)labels[s] * 128 + j];
  __syncthreads();
  float a = B1[j];
  for (int k = 0; k < 128; ++k) a += cond[k] * W1[k * 128 + j];
  hid[j] = fmaxf(a, 0.f);
  __syncthreads();
  float p = B2[j];
  for (int k = 0; k < 128; ++k) p += hid[k] * W2[k * 128 + j];
  film[(size_t)((which * 2 + (j >> 6)) * 32 + s) * 64 + (j & 63)] = p;
}

// ---------------- weight generation: h2 @ hw3 + hb3, scatter to swizzled bf16 ----------
// 576 blocks x 256 threads. Thread = 2 cols (float2) x 8 samples. 4-deep
// register pipeline: each 8-load group is issued 3 compute-phases (~768cy)
// before its compute consumes it -> HBM latency (~900cy) mostly covered.
__launch_bounds__(256)
__global__ void wgen_kernel(const float* __restrict__ h2T, const float* __restrict__ hw3,
                            const float* __restrict__ hb3, unsigned short* __restrict__ W) {
  __shared__ float h2l[8192];                       // [k=256][s=32]
  const int t = threadIdx.x;
  for (int i = t; i < 8192; i += 256) h2l[i] = h2T[i];
  __syncthreads();
  const int lane = t & 63, sg = t >> 6;
  const int j0 = blockIdx.x * 128 + lane * 2;
  const float* __restrict__ gp = hw3 + j0;
  const float* __restrict__ hp = h2l + sg * 8;

  float acc[16];                                    // [sample i][col c] = acc[i*2+c]
  #pragma unroll
  for (int i = 0; i < 16; ++i) acc[i] = 0.f;

  float2 bA[8], bB[8], bC[8], bD[8];
  #pragma unroll
  for (int u = 0; u < 8; ++u) bA[u] = *(const float2*)(gp + (size_t)(u) * 73728);
  #pragma unroll
  for (int u = 0; u < 8; ++u) bB[u] = *(const float2*)(gp + (size_t)(8 + u) * 73728);
  #pragma unroll
  for (int u = 0; u < 8; ++u) bC[u] = *(const float2*)(gp + (size_t)(16 + u) * 73728);

#define WG_COMPUTE(BUF, KB)                                                    \
  _Pragma("unroll")                                                            \
  for (int u = 0; u < 8; ++u) {                                                \
    const float4 hA = *(const float4*)(hp + ((KB) + u) * 32);                  \
    const float4 hB = *(const float4*)(hp + ((KB) + u) * 32 + 4);              \
    const float2 wv = BUF[u];                                                  \
    acc[0]  += hA.x * wv.x; acc[1]  += hA.x * wv.y;                            \
    acc[2]  += hA.y * wv.x; acc[3]  += hA.y * wv.y;                            \
    acc[4]  += hA.z * wv.x; acc[5]  += hA.z * wv.y;                            \
    acc[6]  += hA.w * wv.x; acc[7]  += hA.w * wv.y;                            \
    acc[8]  += hB.x * wv.x; acc[9]  += hB.x * wv.y;                            \
    acc[10] += hB.y * wv.x; acc[11] += hB.y * wv.y;                            \
    acc[12] += hB.z * wv.x; acc[13] += hB.z * wv.y;                            \
    acc[14] += hB.w * wv.x; acc[15] += hB.w * wv.y;                            \
  }

  #pragma unroll 1
  for (int kc = 0; kc < 256; kc += 32) {
    #pragma unroll
    for (int u = 0; u < 8; ++u) bD[u] = *(const float2*)(gp + (size_t)(kc + 24 + u) * 73728);
    WG_COMPUTE(bA, kc)
    if (kc < 224) {
      #pragma unroll
      for (int u = 0; u < 8; ++u) bA[u] = *(const float2*)(gp + (size_t)(kc + 32 + u) * 73728);
    }
    WG_COMPUTE(bB, kc + 8)
    if (kc < 224) {
      #pragma unroll
      for (int u = 0; u < 8; ++u) bB[u] = *(const float2*)(gp + (size_t)(kc + 40 + u) * 73728);
    }
    WG_COMPUTE(bC, kc + 16)
    if (kc < 224) {
      #pragma unroll
      for (int u = 0; u < 8; ++u) bC[u] = *(const float2*)(gp + (size_t)(kc + 48 + u) * 73728);
    }
    WG_COMPUTE(bD, kc + 24)
  }
#undef WG_COMPUTE

  #pragma unroll
  for (int c = 0; c < 2; ++c) {
    const int j  = j0 + c;
    const float bias = hb3[j];
    const int cv = j / 36864;               // which conv
    const int r  = j - cv * 36864;
    const int co = r / 576;
    const int r2 = r - co * 576;
    const int ci = r2 / 9;
    const int tap = r2 - ci * 9;            // ky*3+kx
    const int sw = (co * 64 + ci) ^ ((co & 7) << 3);   // ushort-unit swizzle (byte<<4)
    #pragma unroll
    for (int i = 0; i < 8; ++i) {
      const int s2 = sg * 8 + i;
      W[(size_t)((s2 * 2 + cv) * 9 + tap) * 4096 + sw] = f2bf(acc[i * 2 + c] + bias);
    }
  }
}

// ---------------- initial grid: [B,C,H,W] f32 -> swizzled channels-last bf16 -----------
__global__ void init_kernel(const float* __restrict__ gin, unsigned short* __restrict__ g0) {
  __shared__ float lds[64][65];                     // +1 pad
  const int b = blockIdx.x >> 6, y = blockIdx.x & 63;   // 2048 blocks x 256 threads
  const int t = threadIdx.x;
  {
    const int ci = t >> 2, xq = t & 3;
    const float* base = gin + (size_t)((b * 64 + ci) * 64 + y) * 64;
    #pragma unroll
    for (int q = 0; q < 4; ++q) {
      const int x0 = (xq + q * 4) * 4;
      const float4 v = *(const float4*)(base + x0);
      lds[ci][x0+0] = v.x; lds[ci][x0+1] = v.y; lds[ci][x0+2] = v.z; lds[ci][x0+3] = v.w;
    }
  }
  __syncthreads();
  const int x = t >> 2, cq = t & 3, ci0 = cq * 16;
  us8 lo, hi;
  #pragma unroll
  for (int i = 0; i < 8; ++i) lo[i] = f2bf(lds[ci0 + i][x]);
  #pragma unroll
  for (int i = 0; i < 8; ++i) hi[i] = f2bf(lds[ci0 + 8 + i][x]);
  char* dbase = (char*)(g0 + (size_t)(b * 64 + y) * 4096);
  const int o = x * 128 + ci0 * 2, sw = (x & 7) << 4;
  *(us8*)(dbase + (o ^ sw)) = lo;
  *(us8*)(dbase + ((o + 16) ^ sw)) = hi;
}

// ---------------- the conv step kernel -------------------------------------------------
// WHICH=0: u = relu(g1*conv(grid,W1)+be1)            src=grid, dst=u
// WHICH=1: u2 = relu(g2*conv(u,W2)+be2); grid' = (1-bs)*grid + bs*u2; rgb out
// Block: 512 thr (8 waves) = one sample x 8 output rows x all 64 co x all 64 x.
// XCD-binding swizzle: blocks of sample s land on XCD s%8.
// Tap loop is ping-pong software-pipelined in registers: tap t+1's 16
// ds_read_b128 issue before tap t's 32 MFMAs.
template<int WHICH>
__launch_bounds__(512, 2)
__global__ void conv_kernel(const unsigned short* __restrict__ Wall,
                            const unsigned short* __restrict__ src,
                            unsigned short* __restrict__ dst,
                            const unsigned short* __restrict__ gold,
                            const float* __restrict__ film,
                            const float* __restrict__ blendp,
                            float* __restrict__ out, int t) {
  __shared__ unsigned short in_lds[10 * 4096];      // rows y0-1..y0+8, [x][ci] swizzled
  __shared__ unsigned short w_lds[9 * 4096];        // [tap][co][ci] swizzled
  const int tid  = threadIdx.x;
  const int wid  = tid >> 6;                        // wave id -> output row
  const int lane = tid & 63;
  const int l15  = lane & 15;
  const int lhi  = lane >> 4;
  const int b    = blockIdx.x;
  const int s    = (b & 7) + 8 * ((b >> 3) & 3);    // sample -> XCD b&7 == s%8
  const int y0   = (b >> 5) * 8;

  const unsigned short* srcs = src + (size_t)s * 262144;
  const unsigned short* Wb   = Wall + (size_t)((s * 2 + WHICH) * 9) * 4096;

  // stage 10 input rows: 80 x 1KB wave-chunks (10 per wave)
  #pragma unroll
  for (int q = 0; q < 10; ++q) {
    const int c   = q * 8 + wid;
    const int row = c >> 3, part = c & 7;
    const int gy  = (y0 + row + 63) & 63;
    gl_lds16(srcs + gy * 4096 + part * 512 + lane * 8, &in_lds[row * 4096 + part * 512]);
  }
  // stage all 9 taps of weights: 72 x 1KB wave-chunks (9 per wave)
  #pragma unroll
  for (int q = 0; q < 9; ++q) {
    const int c = q * 8 + wid;
    gl_lds16(Wb + c * 512 + lane * 8, &w_lds[c * 512]);
  }
  asm volatile("s_waitcnt vmcnt(0)" ::: "memory");
  __syncthreads();

  f32x4 acc[4][4];
  #pragma unroll
  for (int m = 0; m < 4; ++m)
    #pragma unroll
    for (int n = 0; n < 4; ++n)
      #pragma unroll
      for (int j = 0; j < 4; ++j) acc[m][n][j] = 0.f;

  short8 afA[4][2], bfA[4][2], afB[4][2], bfB[4][2];

#define CONV_LOAD(AF, BF, TAP)                                                  \
  {                                                                             \
    const int ky = (TAP) / 3, kx = (TAP) % 3;                                   \
    _Pragma("unroll")                                                           \
    for (int m = 0; m < 4; ++m) {                                               \
      const int co = m * 16 + l15;                                              \
      _Pragma("unroll")                                                         \
      for (int kk = 0; kk < 2; ++kk) {                                          \
        const int off = (TAP) * 8192 +                                          \
            ((co * 128 + kk * 64 + lhi * 16) ^ ((co & 7) << 4));                \
        AF[m][kk] = *(const short8*)((const char*)w_lds + off);                 \
      }                                                                         \
    }                                                                           \
    const int r = wid + ky;                                                     \
    _Pragma("unroll")                                                           \
    for (int n = 0; n < 4; ++n) {                                               \
      const int xs = (n * 16 + l15 + kx + 63) & 63;                             \
      _Pragma("unroll")                                                         \
      for (int kk = 0; kk < 2; ++kk) {                                          \
        const int off = r * 8192 +                                              \
            ((xs * 128 + kk * 64 + lhi * 16) ^ ((xs & 7) << 4));                \
        BF[n][kk] = *(const short8*)((const char*)in_lds + off);                \
      }                                                                         \
    }                                                                           \
  }

#define CONV_MMAC(AF, BF)                                                       \
  __builtin_amdgcn_s_setprio(1);                                                \
  _Pragma("unroll")                                                             \
  for (int kk = 0; kk < 2; ++kk)                                                \
    _Pragma("unroll")                                                           \
    for (int m = 0; m < 4; ++m)                                                 \
      _Pragma("unroll")                                                         \
      for (int n = 0; n < 4; ++n)                                               \
        acc[m][n] = __builtin_amdgcn_mfma_f32_16x16x32_bf16(                    \
            AF[m][kk], BF[n][kk], acc[m][n], 0, 0, 0);                          \
  __builtin_amdgcn_s_setprio(0);

  CONV_LOAD(afA, bfA, 0)
  CONV_LOAD(afB, bfB, 1)  CONV_MMAC(afA, bfA)
  CONV_LOAD(afA, bfA, 2)  CONV_MMAC(afB, bfB)
  CONV_LOAD(afB, bfB, 3)  CONV_MMAC(afA, bfA)
  CONV_LOAD(afA, bfA, 4)  CONV_MMAC(afB, bfB)
  CONV_LOAD(afB, bfB, 5)  CONV_MMAC(afA, bfA)
  CONV_LOAD(afA, bfA, 6)  CONV_MMAC(afB, bfB)
  CONV_LOAD(afB, bfB, 7)  CONV_MMAC(afA, bfA)
  CONV_LOAD(afA, bfA, 8)  CONV_MMAC(afB, bfB)
  CONV_MMAC(afA, bfA)
#undef CONV_LOAD
#undef CONV_MMAC

  // ---- epilogue: FiLM + relu (+ blend + rgb for WHICH=1) ----
  const int y = y0 + wid;
  const float* fg = film + WHICH * 2 * 2048;        // g  [32][64]
  const float* fb = fg + 2048;                      // be [32][64]
  float bs = 0.f, obs = 0.f;
  if (WHICH == 1) { bs = 1.f / (1.f + expf(-blendp[0])); obs = 1.f - bs; }
  unsigned short* drow = dst + (size_t)s * 262144 + y * 4096;
  const unsigned short* grow = (WHICH == 1) ? (gold + (size_t)s * 262144 + y * 4096) : (const unsigned short*)nullptr;

  #pragma unroll
  for (int m = 0; m < 4; ++m) {
    const int co0 = m * 16 + lhi * 4;               // C/D: row(co) = lhi*4 + reg (m89)
    const float4 g  = *(const float4*)&fg[s * 64 + co0];
    const float4 be = *(const float4*)&fb[s * 64 + co0];
    #pragma unroll
    for (int n = 0; n < 4; ++n) {
      const int x = n * 16 + l15;                   // C/D: col(x) = lane&15
      const int off = (x * 128 + co0 * 2) ^ ((x & 7) << 4);
      const f32x4 v = acc[m][n];
      const float u0 = fmaxf(g.x * v[0] + be.x, 0.f);
      const float u1 = fmaxf(g.y * v[1] + be.y, 0.f);
      const float u2 = fmaxf(g.z * v[2] + be.z, 0.f);
      const float u3 = fmaxf(g.w * v[3] + be.w, 0.f);
      if (WHICH == 0) {
        ushort4 pk; pk.x = f2bf(u0); pk.y = f2bf(u1); pk.z = f2bf(u2); pk.w = f2bf(u3);
        *(ushort4*)((char*)drow + off) = pk;
      } else {
        const ushort4 od = *(const ushort4*)((const char*)grow + off);
        const float g0 = obs * bf2f(od.x) + bs * u0;
        const float g1 = obs * bf2f(od.y) + bs * u1;
        const float g2 = obs * bf2f(od.z) + bs * u2;
        const float g3 = obs * bf2f(od.w) + bs * u3;
        ushort4 pk; pk.x = f2bf(g0); pk.y = f2bf(g1); pk.z = f2bf(g2); pk.w = f2bf(g3);
        *(ushort4*)((char*)drow + off) = pk;
        if (co0 == 0) {                             // rgb channels 0..2
          const float r0 = 1.f / (1.f + expf(-g0));
          const float r1 = 1.f / (1.f + expf(-g1));
          const float r2 = 1.f / (1.f + expf(-g2));
          float* ob = out + 393216 + (size_t)((t * 32 + s) * 3) * 4096 + y * 64 + x;
          ob[0] = r0; ob[4096] = r1; ob[8192] = r2;
          if (t == 31) {                            // traj[-1] head copy
            float* o2 = out + (size_t)(s * 3) * 4096 + y * 64 + x;
            o2[0] = r0; o2[4096] = r1; o2[8192] = r2;
          }
        }
      }
    }
  }
}

extern "C" void kernel_launch(void* const* d_in, const int* in_sizes, int n_in,
                              void* d_out, int out_size, void* d_ws, size_t ws_size,
                              hipStream_t stream) {
  (void)in_sizes; (void)n_in; (void)out_size; (void)ws_size;
  const int*   labels = (const int*)d_in[0];
  const float* gin    = (const float*)d_in[1];
  const float* emb    = (const float*)d_in[2];
  const float* hw1    = (const float*)d_in[3];
  const float* hb1    = (const float*)d_in[4];
  const float* hw2    = (const float*)d_in[5];
  const float* hb2    = (const float*)d_in[6];
  const float* hw3    = (const float*)d_in[7];
  const float* hb3    = (const float*)d_in[8];
  const float* f1w1   = (const float*)d_in[9];
  const float* f1b1   = (const float*)d_in[10];
  const float* f1w2   = (const float*)d_in[11];
  const float* f1b2   = (const float*)d_in[12];
  const float* f2w1   = (const float*)d_in[13];
  const float* f2b1   = (const float*)d_in[14];
  const float* f2w2   = (const float*)d_in[15];
  const float* f2b2   = (const float*)d_in[16];
  const float* blend  = (const float*)d_in[17];
  float* out = (float*)d_out;

  char* ws = (char*)d_ws;                               // ~55.1 MB used
  unsigned short* grid0 = (unsigned short*)(ws + (size_t)0);         // 16 MB
  unsigned short* grid1 = (unsigned short*)(ws + (size_t)16777216);  // 16 MB
  unsigned short* ubuf  = (unsigned short*)(ws + (size_t)33554432);  // 16 MB
  unsigned short* Wbuf  = (unsigned short*)(ws + (size_t)50331648);  // 4.72 MB
  float* h2T  = (float*)(ws + (size_t)55050240);                     // 32 KB
  float* film = (float*)(ws + (size_t)55083008);                     // 32 KB

  hyper_kernel<<<32, 256, 0, stream>>>(labels, emb, hw1, hb1, hw2, hb2, h2T);
  film_kernel<<<dim3(32, 2), 128, 0, stream>>>(labels, emb, f1w1, f1b1, f1w2, f1b2,
                                               f2w1, f2b1, f2w2, f2b2, film);
  wgen_kernel<<<576, 256, 0, stream>>>(h2T, hw3, hb3, Wbuf);
  init_kernel<<<2048, 256, 0, stream>>>(gin, grid0);

  for (int t = 0; t < 32; ++t) {
    unsigned short* gi = (t & 1) ? grid1 : grid0;
    unsigned short* go = (t & 1) ? grid0 : grid1;
    conv_kernel<0><<<256, 512, 0, stream>>>(Wbuf, gi, ubuf, nullptr, film, nullptr, nullptr, t);
    conv_kernel<1><<<256, 512, 0, stream>>>(Wbuf, ubuf, go, gi, film, blend, out, t);
  }
}

// Round 9
// 1216.617 us; speedup vs baseline: 1.0143x; 1.0143x over previous
//
#include <hip/hip_runtime.h>

// NCA with hypernetwork, MI355X bf16-MFMA implementation (round 9).
//
// Layouts (all in d_ws, rebuilt every call since ws is poisoned):
//   grid0/grid1/u : bf16, channels-last [s][y][x][ci], per-(y,x) 128B "ci-line",
//                   byte-swizzled  byte ^= ((x&7)<<4)   (bank-conflict-free ds_read_b128)
//   Wbuf          : bf16, [s][conv][tap][co][ci], per-co 128B ci-line,
//                   byte-swizzled  byte ^= ((co&7)<<4)
//
// Round-9 change (wgen only; conv byte-identical to round 8):
//   * wgen: LDS-staged double-buffer via global_load_lds. Round-8's 4-deep
//     REGISTER pipeline hit VGPR 172 -> occupancy halved (15%->8%), 60->71us.
//     Now in-flight bytes live in the gl_lds queue, not the RF: 8 chunks of
//     32k x 128cols (16KB) double-buffered, chunk n+1 issued before computing
//     chunk n (~1500cy compute >> ~900cy HBM latency). acc[16]/thread, ~55
//     VGPR -> high TLP + deep prefetch simultaneously.

typedef __attribute__((ext_vector_type(8))) short short8;     // 8 bf16 = 4 VGPR (MFMA frag)
typedef __attribute__((ext_vector_type(4))) float f32x4;      // MFMA acc frag
typedef __attribute__((ext_vector_type(8))) unsigned short us8;

__device__ __forceinline__ unsigned short f2bf(float f) {     // RNE f32->bf16
  unsigned int u = __builtin_bit_cast(unsigned int, f);
  u = (u + 0x7FFFu + ((u >> 16) & 1u)) >> 16;
  return (unsigned short)u;
}
__device__ __forceinline__ float bf2f(unsigned short h) {
  unsigned int u = ((unsigned int)h) << 16;
  return __builtin_bit_cast(float, u);
}

__device__ __forceinline__ void gl_lds16(const void* g, void* l) {
  // 16B-wide async global->LDS; LDS dest is wave-uniform base + lane*16 (m104).
  __builtin_amdgcn_global_load_lds((const __attribute__((address_space(1))) void*)g,
                                   (__attribute__((address_space(3))) void*)l, 16, 0, 0);
}

// ---------------- hypernet trunk: cond -> h1 -> h2 (store h2 transposed [k][s]) --------
__global__ void hyper_kernel(const int* __restrict__ labels, const float* __restrict__ emb,
                             const float* __restrict__ hw1, const float* __restrict__ hb1,
                             const float* __restrict__ hw2, const float* __restrict__ hb2,
                             float* __restrict__ h2T) {
  __shared__ float cond[128];
  __shared__ float h1[256];
  const int s = blockIdx.x, j = threadIdx.x;        // 32 blocks x 256 threads
  if (j < 128) cond[j] = emb[(size_t)labels[s] * 128 + j];
  __syncthreads();
  float a = hb1[j];
  for (int k = 0; k < 128; ++k) a += cond[k] * hw1[k * 256 + j];
  h1[j] = fmaxf(a, 0.f);
  __syncthreads();
  float a2 = hb2[j];
  for (int k = 0; k < 256; ++k) a2 += h1[k] * hw2[k * 256 + j];
  h2T[j * 32 + s] = fmaxf(a2, 0.f);                 // [256][32]
}

// ---------------- FiLM params: film[4][32][64] = g1,be1,g2,be2 -------------------------
__global__ void film_kernel(const int* __restrict__ labels, const float* __restrict__ emb,
                            const float* __restrict__ f1w1, const float* __restrict__ f1b1,
                            const float* __restrict__ f1w2, const float* __restrict__ f1b2,
                            const float* __restrict__ f2w1, const float* __restrict__ f2b1,
                            const float* __restrict__ f2w2, const float* __restrict__ f2b2,
                            float* __restrict__ film) {
  __shared__ float cond[128];
  __shared__ float hid[128];
  const int s = blockIdx.x, which = blockIdx.y, j = threadIdx.x;   // (32,2) x 128
  const float* W1 = which ? f2w1 : f1w1;
  const float* B1 = which ? f2b1 : f1b1;
  const float* W2 = which ? f2w2 : f1w2;
  const float* B2 = which ? f2b2 : f1b2;
  cond[j] = emb[(size_t)labels[s] * 128 + j];
  __syncthreads();
  float a = B1[j];
  for (int k = 0; k < 128; ++k) a += cond[k] * W1[k * 128 + j];
  hid[j] = fmaxf(a, 0.f);
  __syncthreads();
  float p = B2[j];
  for (int k = 0; k < 128; ++k) p += hid[k] * W2[k * 128 + j];
  film[(size_t)((which * 2 + (j >> 6)) * 32 + s) * 64 + (j & 63)] = p;
}

// ---------------- weight generation: h2 @ hw3 + hb3, scatter to swizzled bf16 ----------
// 576 blocks x 256 threads. Block = 128 cols x 32 samples; thread = 1 col x 16
// samples (sg = t>>7). hw3 staged through LDS in 8 double-buffered chunks of
// 32k x 128col (16KB) via global_load_lds: chunk n+1's 16 loads issue before
// chunk n's compute (~1500cy/wave) -> HBM latency fully covered, zero VGPR
// spent on in-flight data.
__launch_bounds__(256)
__global__ void wgen_kernel(const float* __restrict__ h2T, const float* __restrict__ hw3,
                            const float* __restrict__ hb3, unsigned short* __restrict__ W) {
  __shared__ float h2l[8192];                       // [k=256][s=32]  32 KB
  __shared__ float wbuf[2][32 * 128];               // [buf][k%32][col] 2x16 KB
  const int t = threadIdx.x;
  for (int i = t; i < 8192; i += 256) h2l[i] = h2T[i];
  const int lane = t & 63, wid = t >> 6;
  const int col = t & 127;                          // block-local col
  const int sg  = t >> 7;                           // sample group (16 samples)
  const int j   = blockIdx.x * 128 + col;           // absolute output col
  const float* __restrict__ hp = h2l + sg * 16;

  // stage instr q (q=0..3 per wave): i = q*4+wid covers k-rows 2i,2i+1 of chunk
  const int i0   = (lane >> 5);                     // sub-row within instr
  const int csub = (lane & 31) << 2;                // col group (4 floats)
#define WG_STAGE(BUF, KC)                                                      \
  _Pragma("unroll")                                                            \
  for (int q = 0; q < 4; ++q) {                                                \
    const int ii = q * 4 + wid;                                                \
    gl_lds16(hw3 + (size_t)((KC) + 2 * ii + i0) * 73728 + blockIdx.x * 128 + csub, \
             &wbuf[BUF][2 * ii * 128]);                                        \
  }

  float acc[16];
  #pragma unroll
  for (int i = 0; i < 16; ++i) acc[i] = 0.f;

  WG_STAGE(0, 0)
  asm volatile("s_waitcnt vmcnt(0)" ::: "memory");
  __syncthreads();                                  // h2l + chunk 0 ready

  int buf = 0;
  #pragma unroll 1
  for (int kc = 0; kc < 256; kc += 32) {
    if (kc + 32 < 256) WG_STAGE(buf ^ 1, kc + 32)   // issue next chunk first
    #pragma unroll
    for (int kk = 0; kk < 32; ++kk) {
      const float wv = wbuf[buf][kk * 128 + col];
      const float4 hA = *(const float4*)(hp + (kc + kk) * 32);
      const float4 hB = *(const float4*)(hp + (kc + kk) * 32 + 4);
      const float4 hC = *(const float4*)(hp + (kc + kk) * 32 + 8);
      const float4 hD = *(const float4*)(hp + (kc + kk) * 32 + 12);
      acc[0]  += hA.x * wv; acc[1]  += hA.y * wv; acc[2]  += hA.z * wv; acc[3]  += hA.w * wv;
      acc[4]  += hB.x * wv; acc[5]  += hB.y * wv; acc[6]  += hB.z * wv; acc[7]  += hB.w * wv;
      acc[8]  += hC.x * wv; acc[9]  += hC.y * wv; acc[10] += hC.z * wv; acc[11] += hC.w * wv;
      acc[12] += hD.x * wv; acc[13] += hD.y * wv; acc[14] += hD.z * wv; acc[15] += hD.w * wv;
    }
    asm volatile("s_waitcnt vmcnt(0)" ::: "memory");
    __syncthreads();                                // next chunk landed; all done with buf
    buf ^= 1;
  }
#undef WG_STAGE

  const float bias = hb3[j];
  const int cv = j / 36864;               // which conv
  const int r  = j - cv * 36864;
  const int co = r / 576;
  const int r2 = r - co * 576;
  const int ci = r2 / 9;
  const int tap = r2 - ci * 9;            // ky*3+kx
  const int sw = (co * 64 + ci) ^ ((co & 7) << 3);   // ushort-unit swizzle (byte<<4)
  #pragma unroll
  for (int i = 0; i < 16; ++i) {
    const int s2 = sg * 16 + i;
    W[(size_t)((s2 * 2 + cv) * 9 + tap) * 4096 + sw] = f2bf(acc[i] + bias);
  }
}

// ---------------- initial grid: [B,C,H,W] f32 -> swizzled channels-last bf16 -----------
__global__ void init_kernel(const float* __restrict__ gin, unsigned short* __restrict__ g0) {
  __shared__ float lds[64][65];                     // +1 pad
  const int b = blockIdx.x >> 6, y = blockIdx.x & 63;   // 2048 blocks x 256 threads
  const int t = threadIdx.x;
  {
    const int ci = t >> 2, xq = t & 3;
    const float* base = gin + (size_t)((b * 64 + ci) * 64 + y) * 64;
    #pragma unroll
    for (int q = 0; q < 4; ++q) {
      const int x0 = (xq + q * 4) * 4;
      const float4 v = *(const float4*)(base + x0);
      lds[ci][x0+0] = v.x; lds[ci][x0+1] = v.y; lds[ci][x0+2] = v.z; lds[ci][x0+3] = v.w;
    }
  }
  __syncthreads();
  const int x = t >> 2, cq = t & 3, ci0 = cq * 16;
  us8 lo, hi;
  #pragma unroll
  for (int i = 0; i < 8; ++i) lo[i] = f2bf(lds[ci0 + i][x]);
  #pragma unroll
  for (int i = 0; i < 8; ++i) hi[i] = f2bf(lds[ci0 + 8 + i][x]);
  char* dbase = (char*)(g0 + (size_t)(b * 64 + y) * 4096);
  const int o = x * 128 + ci0 * 2, sw = (x & 7) << 4;
  *(us8*)(dbase + (o ^ sw)) = lo;
  *(us8*)(dbase + ((o + 16) ^ sw)) = hi;
}

// ---------------- the conv step kernel -------------------------------------------------
// WHICH=0: u = relu(g1*conv(grid,W1)+be1)            src=grid, dst=u
// WHICH=1: u2 = relu(g2*conv(u,W2)+be2); grid' = (1-bs)*grid + bs*u2; rgb out
// Block: 512 thr (8 waves) = one sample x 8 output rows x all 64 co x all 64 x.
// XCD-binding swizzle: blocks of sample s land on XCD s%8.
// Tap loop is ping-pong software-pipelined in registers: tap t+1's 16
// ds_read_b128 issue before tap t's 32 MFMAs.  (byte-identical to round 8)
template<int WHICH>
__launch_bounds__(512, 2)
__global__ void conv_kernel(const unsigned short* __restrict__ Wall,
                            const unsigned short* __restrict__ src,
                            unsigned short* __restrict__ dst,
                            const unsigned short* __restrict__ gold,
                            const float* __restrict__ film,
                            const float* __restrict__ blendp,
                            float* __restrict__ out, int t) {
  __shared__ unsigned short in_lds[10 * 4096];      // rows y0-1..y0+8, [x][ci] swizzled
  __shared__ unsigned short w_lds[9 * 4096];        // [tap][co][ci] swizzled
  const int tid  = threadIdx.x;
  const int wid  = tid >> 6;                        // wave id -> output row
  const int lane = tid & 63;
  const int l15  = lane & 15;
  const int lhi  = lane >> 4;
  const int b    = blockIdx.x;
  const int s    = (b & 7) + 8 * ((b >> 3) & 3);    // sample -> XCD b&7 == s%8
  const int y0   = (b >> 5) * 8;

  const unsigned short* srcs = src + (size_t)s * 262144;
  const unsigned short* Wb   = Wall + (size_t)((s * 2 + WHICH) * 9) * 4096;

  // stage 10 input rows: 80 x 1KB wave-chunks (10 per wave)
  #pragma unroll
  for (int q = 0; q < 10; ++q) {
    const int c   = q * 8 + wid;
    const int row = c >> 3, part = c & 7;
    const int gy  = (y0 + row + 63) & 63;
    gl_lds16(srcs + gy * 4096 + part * 512 + lane * 8, &in_lds[row * 4096 + part * 512]);
  }
  // stage all 9 taps of weights: 72 x 1KB wave-chunks (9 per wave)
  #pragma unroll
  for (int q = 0; q < 9; ++q) {
    const int c = q * 8 + wid;
    gl_lds16(Wb + c * 512 + lane * 8, &w_lds[c * 512]);
  }
  asm volatile("s_waitcnt vmcnt(0)" ::: "memory");
  __syncthreads();

  f32x4 acc[4][4];
  #pragma unroll
  for (int m = 0; m < 4; ++m)
    #pragma unroll
    for (int n = 0; n < 4; ++n)
      #pragma unroll
      for (int j = 0; j < 4; ++j) acc[m][n][j] = 0.f;

  short8 afA[4][2], bfA[4][2], afB[4][2], bfB[4][2];

#define CONV_LOAD(AF, BF, TAP)                                                  \
  {                                                                             \
    const int ky = (TAP) / 3, kx = (TAP) % 3;                                   \
    _Pragma("unroll")                                                           \
    for (int m = 0; m < 4; ++m) {                                               \
      const int co = m * 16 + l15;                                              \
      _Pragma("unroll")                                                         \
      for (int kk = 0; kk < 2; ++kk) {                                          \
        const int off = (TAP) * 8192 +                                          \
            ((co * 128 + kk * 64 + lhi * 16) ^ ((co & 7) << 4));                \
        AF[m][kk] = *(const short8*)((const char*)w_lds + off);                 \
      }                                                                         \
    }                                                                           \
    const int r = wid + ky;                                                     \
    _Pragma("unroll")                                                           \
    for (int n = 0; n < 4; ++n) {                                               \
      const int xs = (n * 16 + l15 + kx + 63) & 63;                             \
      _Pragma("unroll")                                                         \
      for (int kk = 0; kk < 2; ++kk) {                                          \
        const int off = r * 8192 +                                              \
            ((xs * 128 + kk * 64 + lhi * 16) ^ ((xs & 7) << 4));                \
        BF[n][kk] = *(const short8*)((const char*)in_lds + off);                \
      }                                                                         \
    }                                                                           \
  }

#define CONV_MMAC(AF, BF)                                                       \
  __builtin_amdgcn_s_setprio(1);                                                \
  _Pragma("unroll")                                                             \
  for (int kk = 0; kk < 2; ++kk)                                                \
    _Pragma("unroll")                                                           \
    for (int m = 0; m < 4; ++m)                                                 \
      _Pragma("unroll")                                                         \
      for (int n = 0; n < 4; ++n)                                               \
        acc[m][n] = __builtin_amdgcn_mfma_f32_16x16x32_bf16(                    \
            AF[m][kk], BF[n][kk], acc[m][n], 0, 0, 0);                          \
  __builtin_amdgcn_s_setprio(0);

  CONV_LOAD(afA, bfA, 0)
  CONV_LOAD(afB, bfB, 1)  CONV_MMAC(afA, bfA)
  CONV_LOAD(afA, bfA, 2)  CONV_MMAC(afB, bfB)
  CONV_LOAD(afB, bfB, 3)  CONV_MMAC(afA, bfA)
  CONV_LOAD(afA, bfA, 4)  CONV_MMAC(afB, bfB)
  CONV_LOAD(afB, bfB, 5)  CONV_MMAC(afA, bfA)
  CONV_LOAD(afA, bfA, 6)  CONV_MMAC(afB, bfB)
  CONV_LOAD(afB, bfB, 7)  CONV_MMAC(afA, bfA)
  CONV_LOAD(afA, bfA, 8)  CONV_MMAC(afB, bfB)
  CONV_MMAC(afA, bfA)
#undef CONV_LOAD
#undef CONV_MMAC

  // ---- epilogue: FiLM + relu (+ blend + rgb for WHICH=1) ----
  const int y = y0 + wid;
  const float* fg = film + WHICH * 2 * 2048;        // g  [32][64]
  const float* fb = fg + 2048;                      // be [32][64]
  float bs = 0.f, obs = 0.f;
  if (WHICH == 1) { bs = 1.f / (1.f + expf(-blendp[0])); obs = 1.f - bs; }
  unsigned short* drow = dst + (size_t)s * 262144 + y * 4096;
  const unsigned short* grow = (WHICH == 1) ? (gold + (size_t)s * 262144 + y * 4096) : (const unsigned short*)nullptr;

  #pragma unroll
  for (int m = 0; m < 4; ++m) {
    const int co0 = m * 16 + lhi * 4;               // C/D: row(co) = lhi*4 + reg (m89)
    const float4 g  = *(const float4*)&fg[s * 64 + co0];
    const float4 be = *(const float4*)&fb[s * 64 + co0];
    #pragma unroll
    for (int n = 0; n < 4; ++n) {
      const int x = n * 16 + l15;                   // C/D: col(x) = lane&15
      const int off = (x * 128 + co0 * 2) ^ ((x & 7) << 4);
      const f32x4 v = acc[m][n];
      const float u0 = fmaxf(g.x * v[0] + be.x, 0.f);
      const float u1 = fmaxf(g.y * v[1] + be.y, 0.f);
      const float u2 = fmaxf(g.z * v[2] + be.z, 0.f);
      const float u3 = fmaxf(g.w * v[3] + be.w, 0.f);
      if (WHICH == 0) {
        ushort4 pk; pk.x = f2bf(u0); pk.y = f2bf(u1); pk.z = f2bf(u2); pk.w = f2bf(u3);
        *(ushort4*)((char*)drow + off) = pk;
      } else {
        const ushort4 od = *(const ushort4*)((const char*)grow + off);
        const float g0 = obs * bf2f(od.x) + bs * u0;
        const float g1 = obs * bf2f(od.y) + bs * u1;
        const float g2 = obs * bf2f(od.z) + bs * u2;
        const float g3 = obs * bf2f(od.w) + bs * u3;
        ushort4 pk; pk.x = f2bf(g0); pk.y = f2bf(g1); pk.z = f2bf(g2); pk.w = f2bf(g3);
        *(ushort4*)((char*)drow + off) = pk;
        if (co0 == 0) {                             // rgb channels 0..2
          const float r0 = 1.f / (1.f + expf(-g0));
          const float r1 = 1.f / (1.f + expf(-g1));
          const float r2 = 1.f / (1.f + expf(-g2));
          float* ob = out + 393216 + (size_t)((t * 32 + s) * 3) * 4096 + y * 64 + x;
          ob[0] = r0; ob[4096] = r1; ob[8192] = r2;
          if (t == 31) {                            // traj[-1] head copy
            float* o2 = out + (size_t)(s * 3) * 4096 + y * 64 + x;
            o2[0] = r0; o2[4096] = r1; o2[8192] = r2;
          }
        }
      }
    }
  }
}

extern "C" void kernel_launch(void* const* d_in, const int* in_sizes, int n_in,
                              void* d_out, int out_size, void* d_ws, size_t ws_size,
                              hipStream_t stream) {
  (void)in_sizes; (void)n_in; (void)out_size; (void)ws_size;
  const int*   labels = (const int*)d_in[0];
  const float* gin    = (const float*)d_in[1];
  const float* emb    = (const float*)d_in[2];
  const float* hw1    = (const float*)d_in[3];
  const float* hb1    = (const float*)d_in[4];
  const float* hw2    = (const float*)d_in[5];
  const float* hb2    = (const float*)d_in[6];
  const float* hw3    = (const float*)d_in[7];
  const float* hb3    = (const float*)d_in[8];
  const float* f1w1   = (const float*)d_in[9];
  const float* f1b1   = (const float*)d_in[10];
  const float* f1w2   = (const float*)d_in[11];
  const float* f1b2   = (const float*)d_in[12];
  const float* f2w1   = (const float*)d_in[13];
  const float* f2b1   = (const float*)d_in[14];
  const float* f2w2   = (const float*)d_in[15];
  const float* f2b2   = (const float*)d_in[16];
  const float* blend  = (const float*)d_in[17];
  float* out = (float*)d_out;

  char* ws = (char*)d_ws;                               // ~55.1 MB used
  unsigned short* grid0 = (unsigned short*)(ws + (size_t)0);         // 16 MB
  unsigned short* grid1 = (unsigned short*)(ws + (size_t)16777216);  // 16 MB
  unsigned short* ubuf  = (unsigned short*)(ws + (size_t)33554432);  // 16 MB
  unsigned short* Wbuf  = (unsigned short*)(ws + (size_t)50331648);  // 4.72 MB
  float* h2T  = (float*)(ws + (size_t)55050240);                     // 32 KB
  float* film = (float*)(ws + (size_t)55083008);                     // 32 KB

  hyper_kernel<<<32, 256, 0, stream>>>(labels, emb, hw1, hb1, hw2, hb2, h2T);
  film_kernel<<<dim3(32, 2), 128, 0, stream>>>(labels, emb, f1w1, f1b1, f1w2, f1b2,
                                               f2w1, f2b1, f2w2, f2b2, film);
  wgen_kernel<<<576, 256, 0, stream>>>(h2T, hw3, hb3, Wbuf);
  init_kernel<<<2048, 256, 0, stream>>>(gin, grid0);

  for (int t = 0; t < 32; ++t) {
    unsigned short* gi = (t & 1) ? grid1 : grid0;
    unsigned short* go = (t & 1) ? grid0 : grid1;
    conv_kernel<0><<<256, 512, 0, stream>>>(Wbuf, gi, ubuf, nullptr, film, nullptr, nullptr, t);
    conv_kernel<1><<<256, 512, 0, stream>>>(Wbuf, ubuf, go, gi, film, blend, out, t);
  }
}

// Round 11
// 1204.352 us; speedup vs baseline: 1.0246x; 1.0102x over previous
//
#include <hip/hip_runtime.h>

// NCA with hypernetwork, MI355X bf16-MFMA implementation (round 10 kernel,
// resubmit — round 10 failed on container infra; never measured).
//
// Layouts (all in d_ws, rebuilt every call since ws is poisoned):
//   grid0/grid1/u : bf16, channels-last [s][y][x][ci], per-(y,x) 128B "ci-line",
//                   byte-swizzled  byte ^= ((x&7)<<4)   (bank-conflict-free ds_read_b128)
//   Wbuf          : bf16, [s][conv][tap][co][ci], per-co 128B ci-line,
//                   byte-swizzled  byte ^= ((co&7)<<4)
//
// Round-10 change (wgen only; conv byte-identical to rounds 8/9):
//   * wgen as MFMA GEMM. Rounds 4/8/9 all converged at ~60us: per-CU the ONE
//     LDS pipe ate ~54cy/k/wave of h-reads vs 8cy/SIMD of VALU -> LDS-bound.
//     Now: C[col][s] = sum_k hw3[k,col]*h2[k,s] via mfma_f32_16x16x32_bf16.
//     h2 packed once into frag-ordered bf16 LDS (2 conflict-free ds_read_b128
//     per K-step), hw3 streamed f32->bf16 in-reg (double-buffered), 16 MFMAs
//     replace 1024 VALU FMAs per wave. 1152 blocks = 18 waves/CU.

typedef __attribute__((ext_vector_type(8))) short short8;     // 8 bf16 = 4 VGPR (MFMA frag)
typedef __attribute__((ext_vector_type(4))) float f32x4;      // MFMA acc frag
typedef __attribute__((ext_vector_type(8))) unsigned short us8;

__device__ __forceinline__ unsigned short f2bf(float f) {     // RNE f32->bf16
  unsigned int u = __builtin_bit_cast(unsigned int, f);
  u = (u + 0x7FFFu + ((u >> 16) & 1u)) >> 16;
  return (unsigned short)u;
}
__device__ __forceinline__ float bf2f(unsigned short h) {
  unsigned int u = ((unsigned int)h) << 16;
  return __builtin_bit_cast(float, u);
}

__device__ __forceinline__ void gl_lds16(const void* g, void* l) {
  // 16B-wide async global->LDS; LDS dest is wave-uniform base + lane*16 (m104).
  __builtin_amdgcn_global_load_lds((const __attribute__((address_space(1))) void*)g,
                                   (__attribute__((address_space(3))) void*)l, 16, 0, 0);
}

// ---------------- hypernet trunk: cond -> h1 -> h2 (store h2 transposed [k][s]) --------
__global__ void hyper_kernel(const int* __restrict__ labels, const float* __restrict__ emb,
                             const float* __restrict__ hw1, const float* __restrict__ hb1,
                             const float* __restrict__ hw2, const float* __restrict__ hb2,
                             float* __restrict__ h2T) {
  __shared__ float cond[128];
  __shared__ float h1[256];
  const int s = blockIdx.x, j = threadIdx.x;        // 32 blocks x 256 threads
  if (j < 128) cond[j] = emb[(size_t)labels[s] * 128 + j];
  __syncthreads();
  float a = hb1[j];
  for (int k = 0; k < 128; ++k) a += cond[k] * hw1[k * 256 + j];
  h1[j] = fmaxf(a, 0.f);
  __syncthreads();
  float a2 = hb2[j];
  for (int k = 0; k < 256; ++k) a2 += h1[k] * hw2[k * 256 + j];
  h2T[j * 32 + s] = fmaxf(a2, 0.f);                 // [256][32]
}

// ---------------- FiLM params: film[4][32][64] = g1,be1,g2,be2 -------------------------
__global__ void film_kernel(const int* __restrict__ labels, const float* __restrict__ emb,
                            const float* __restrict__ f1w1, const float* __restrict__ f1b1,
                            const float* __restrict__ f1w2, const float* __restrict__ f1b2,
                            const float* __restrict__ f2w1, const float* __restrict__ f2b1,
                            const float* __restrict__ f2w2, const float* __restrict__ f2b2,
                            float* __restrict__ film) {
  __shared__ float cond[128];
  __shared__ float hid[128];
  const int s = blockIdx.x, which = blockIdx.y, j = threadIdx.x;   // (32,2) x 128
  const float* W1 = which ? f2w1 : f1w1;
  const float* B1 = which ? f2b1 : f1b1;
  const float* W2 = which ? f2w2 : f1w2;
  const float* B2 = which ? f2b2 : f1b2;
  cond[j] = emb[(size_t)labels[s] * 128 + j];
  __syncthreads();
  float a = B1[j];
  for (int k = 0; k < 128; ++k) a += cond[k] * W1[k * 128 + j];
  hid[j] = fmaxf(a, 0.f);
  __syncthreads();
  float p = B2[j];
  for (int k = 0; k < 128; ++k) p += hid[k] * W2[k * 128 + j];
  film[(size_t)((which * 2 + (j >> 6)) * 32 + s) * 64 + (j & 63)] = p;
}

// ---------------- weight generation: MFMA GEMM h2 x hw3 + hb3 -> swizzled bf16 --------
// 1152 blocks x 256 threads (4 waves). Wave = 16 cols x 32 samples x 256 k:
//   A-frag = hw3[16 col x 32 k] (f32 stream -> bf16 in-reg, double-buffered)
//   B-frag = h2 [32 k x 16 s] x 2 halves, from frag-ordered bf16 LDS (built once)
//   2 MFMAs per K-step, 8 K-steps. acc f32x4 x 2.
// Frag conventions identical to conv_kernel (numerically verified): per-lane
// short8 elem j <-> k = kstep*32 + (lane>>4)*8 + j; 16-dim = lane&15;
// C/D: row(=col j) = (lane>>4)*4 + reg, col(=sample) = lane&15.
__launch_bounds__(256)
__global__ void wgen_kernel(const float* __restrict__ h2T, const float* __restrict__ hw3,
                            const float* __restrict__ hb3, unsigned short* __restrict__ W) {
  __shared__ unsigned int h2f[4096];                // 16 KB bf16 frag-ordered
  const int t = threadIdx.x;
  // build h2f: idx = (kstep*2 + half)*256 + lane*4 + jd ; pair (k, k+1) at
  // k = kstep*32 + (lane>>4)*8 + jd*2 ; s = half*16 + (lane&15)
  #pragma unroll
  for (int d = 0; d < 16; ++d) {
    const int idx = d * 256 + t;
    const int jd = idx & 3, ln = (idx >> 2) & 63, kh = idx >> 8;
    const int k  = (kh >> 1) * 32 + (ln >> 4) * 8 + jd * 2;
    const int s  = (kh & 1) * 16 + (ln & 15);
    const float f0 = h2T[k * 32 + s];
    const float f1 = h2T[(k + 1) * 32 + s];
    h2f[idx] = (unsigned int)f2bf(f0) | ((unsigned int)f2bf(f1) << 16);
  }
  __syncthreads();

  const int lane = t & 63, wid = t >> 6;
  const int l15 = lane & 15, lhi = lane >> 4;
  const int col0 = blockIdx.x * 64 + wid * 16;
  const float* __restrict__ ap = hw3 + (size_t)(lhi * 8) * 73728 + col0 + l15;

  f32x4 acc0 = {0.f, 0.f, 0.f, 0.f}, acc1 = {0.f, 0.f, 0.f, 0.f};
  float aA[8], aB[8];
  #pragma unroll
  for (int j2 = 0; j2 < 8; ++j2) aA[j2] = ap[(size_t)j2 * 73728];

#define WG_STEP(CUR, NXT, KS)                                                  \
  {                                                                            \
    if ((KS) < 7) {                                                            \
      _Pragma("unroll")                                                        \
      for (int j2 = 0; j2 < 8; ++j2)                                           \
        NXT[j2] = ap[(size_t)(((KS) + 1) * 32 + j2) * 73728];                  \
    }                                                                          \
    us8 av;                                                                    \
    _Pragma("unroll")                                                          \
    for (int j2 = 0; j2 < 8; ++j2) av[j2] = f2bf(CUR[j2]);                     \
    const short8 afr = __builtin_bit_cast(short8, av);                         \
    const short8 b0 = *(const short8*)&h2f[((KS) * 2 + 0) * 256 + lane * 4];   \
    const short8 b1 = *(const short8*)&h2f[((KS) * 2 + 1) * 256 + lane * 4];   \
    acc0 = __builtin_amdgcn_mfma_f32_16x16x32_bf16(afr, b0, acc0, 0, 0, 0);    \
    acc1 = __builtin_amdgcn_mfma_f32_16x16x32_bf16(afr, b1, acc1, 0, 0, 0);    \
  }

  WG_STEP(aA, aB, 0)
  WG_STEP(aB, aA, 1)
  WG_STEP(aA, aB, 2)
  WG_STEP(aB, aA, 3)
  WG_STEP(aA, aB, 4)
  WG_STEP(aB, aA, 5)
  WG_STEP(aA, aB, 6)
  WG_STEP(aB, aA, 7)
#undef WG_STEP

  // epilogue: lane holds C[col=col0+lhi*4+r][s=l15 (acc0) / l15+16 (acc1)]
  #pragma unroll
  for (int r = 0; r < 4; ++r) {
    const int j = col0 + lhi * 4 + r;
    const float bias = hb3[j];
    const int cv  = j / 36864;
    const int rr  = j - cv * 36864;
    const int co  = rr / 576;
    const int r2  = rr - co * 576;
    const int ci  = r2 / 9;
    const int tap = r2 - ci * 9;
    const int sw  = (co * 64 + ci) ^ ((co & 7) << 3);  // ushort-unit swizzle
    W[(size_t)(((l15)      * 2 + cv) * 9 + tap) * 4096 + sw] = f2bf(acc0[r] + bias);
    W[(size_t)(((l15 + 16) * 2 + cv) * 9 + tap) * 4096 + sw] = f2bf(acc1[r] + bias);
  }
}

// ---------------- initial grid: [B,C,H,W] f32 -> swizzled channels-last bf16 -----------
__global__ void init_kernel(const float* __restrict__ gin, unsigned short* __restrict__ g0) {
  __shared__ float lds[64][65];                     // +1 pad
  const int b = blockIdx.x >> 6, y = blockIdx.x & 63;   // 2048 blocks x 256 threads
  const int t = threadIdx.x;
  {
    const int ci = t >> 2, xq = t & 3;
    const float* base = gin + (size_t)((b * 64 + ci) * 64 + y) * 64;
    #pragma unroll
    for (int q = 0; q < 4; ++q) {
      const int x0 = (xq + q * 4) * 4;
      const float4 v = *(const float4*)(base + x0);
      lds[ci][x0+0] = v.x; lds[ci][x0+1] = v.y; lds[ci][x0+2] = v.z; lds[ci][x0+3] = v.w;
    }
  }
  __syncthreads();
  const int x = t >> 2, cq = t & 3, ci0 = cq * 16;
  us8 lo, hi;
  #pragma unroll
  for (int i = 0; i < 8; ++i) lo[i] = f2bf(lds[ci0 + i][x]);
  #pragma unroll
  for (int i = 0; i < 8; ++i) hi[i] = f2bf(lds[ci0 + 8 + i][x]);
  char* dbase = (char*)(g0 + (size_t)(b * 64 + y) * 4096);
  const int o = x * 128 + ci0 * 2, sw = (x & 7) << 4;
  *(us8*)(dbase + (o ^ sw)) = lo;
  *(us8*)(dbase + ((o + 16) ^ sw)) = hi;
}

// ---------------- the conv step kernel -------------------------------------------------
// WHICH=0: u = relu(g1*conv(grid,W1)+be1)            src=grid, dst=u
// WHICH=1: u2 = relu(g2*conv(u,W2)+be2); grid' = (1-bs)*grid + bs*u2; rgb out
// Block: 512 thr (8 waves) = one sample x 8 output rows x all 64 co x all 64 x.
// XCD-binding swizzle: blocks of sample s land on XCD s%8.
// Tap loop is ping-pong software-pipelined in registers.  (byte-identical to r8/r9)
template<int WHICH>
__launch_bounds__(512, 2)
__global__ void conv_kernel(const unsigned short* __restrict__ Wall,
                            const unsigned short* __restrict__ src,
                            unsigned short* __restrict__ dst,
                            const unsigned short* __restrict__ gold,
                            const float* __restrict__ film,
                            const float* __restrict__ blendp,
                            float* __restrict__ out, int t) {
  __shared__ unsigned short in_lds[10 * 4096];      // rows y0-1..y0+8, [x][ci] swizzled
  __shared__ unsigned short w_lds[9 * 4096];        // [tap][co][ci] swizzled
  const int tid  = threadIdx.x;
  const int wid  = tid >> 6;                        // wave id -> output row
  const int lane = tid & 63;
  const int l15  = lane & 15;
  const int lhi  = lane >> 4;
  const int b    = blockIdx.x;
  const int s    = (b & 7) + 8 * ((b >> 3) & 3);    // sample -> XCD b&7 == s%8
  const int y0   = (b >> 5) * 8;

  const unsigned short* srcs = src + (size_t)s * 262144;
  const unsigned short* Wb   = Wall + (size_t)((s * 2 + WHICH) * 9) * 4096;

  // stage 10 input rows: 80 x 1KB wave-chunks (10 per wave)
  #pragma unroll
  for (int q = 0; q < 10; ++q) {
    const int c   = q * 8 + wid;
    const int row = c >> 3, part = c & 7;
    const int gy  = (y0 + row + 63) & 63;
    gl_lds16(srcs + gy * 4096 + part * 512 + lane * 8, &in_lds[row * 4096 + part * 512]);
  }
  // stage all 9 taps of weights: 72 x 1KB wave-chunks (9 per wave)
  #pragma unroll
  for (int q = 0; q < 9; ++q) {
    const int c = q * 8 + wid;
    gl_lds16(Wb + c * 512 + lane * 8, &w_lds[c * 512]);
  }
  asm volatile("s_waitcnt vmcnt(0)" ::: "memory");
  __syncthreads();

  f32x4 acc[4][4];
  #pragma unroll
  for (int m = 0; m < 4; ++m)
    #pragma unroll
    for (int n = 0; n < 4; ++n)
      #pragma unroll
      for (int j = 0; j < 4; ++j) acc[m][n][j] = 0.f;

  short8 afA[4][2], bfA[4][2], afB[4][2], bfB[4][2];

#define CONV_LOAD(AF, BF, TAP)                                                  \
  {                                                                             \
    const int ky = (TAP) / 3, kx = (TAP) % 3;                                   \
    _Pragma("unroll")                                                           \
    for (int m = 0; m < 4; ++m) {                                               \
      const int co = m * 16 + l15;                                              \
      _Pragma("unroll")                                                         \
      for (int kk = 0; kk < 2; ++kk) {                                          \
        const int off = (TAP) * 8192 +                                          \
            ((co * 128 + kk * 64 + lhi * 16) ^ ((co & 7) << 4));                \
        AF[m][kk] = *(const short8*)((const char*)w_lds + off);                 \
      }                                                                         \
    }                                                                           \
    const int r = wid + ky;                                                     \
    _Pragma("unroll")                                                           \
    for (int n = 0; n < 4; ++n) {                                               \
      const int xs = (n * 16 + l15 + kx + 63) & 63;                             \
      _Pragma("unroll")                                                         \
      for (int kk = 0; kk < 2; ++kk) {                                          \
        const int off = r * 8192 +                                              \
            ((xs * 128 + kk * 64 + lhi * 16) ^ ((xs & 7) << 4));                \
        BF[n][kk] = *(const short8*)((const char*)in_lds + off);                \
      }                                                                         \
    }                                                                           \
  }

#define CONV_MMAC(AF, BF)                                                       \
  __builtin_amdgcn_s_setprio(1);                                                \
  _Pragma("unroll")                                                             \
  for (int kk = 0; kk < 2; ++kk)                                                \
    _Pragma("unroll")                                                           \
    for (int m = 0; m < 4; ++m)                                                 \
      _Pragma("unroll")                                                         \
      for (int n = 0; n < 4; ++n)                                               \
        acc[m][n] = __builtin_amdgcn_mfma_f32_16x16x32_bf16(                    \
            AF[m][kk], BF[n][kk], acc[m][n], 0, 0, 0);                          \
  __builtin_amdgcn_s_setprio(0);

  CONV_LOAD(afA, bfA, 0)
  CONV_LOAD(afB, bfB, 1)  CONV_MMAC(afA, bfA)
  CONV_LOAD(afA, bfA, 2)  CONV_MMAC(afB, bfB)
  CONV_LOAD(afB, bfB, 3)  CONV_MMAC(afA, bfA)
  CONV_LOAD(afA, bfA, 4)  CONV_MMAC(afB, bfB)
  CONV_LOAD(afB, bfB, 5)  CONV_MMAC(afA, bfA)
  CONV_LOAD(afA, bfA, 6)  CONV_MMAC(afB, bfB)
  CONV_LOAD(afB, bfB, 7)  CONV_MMAC(afA, bfA)
  CONV_LOAD(afA, bfA, 8)  CONV_MMAC(afB, bfB)
  CONV_MMAC(afA, bfA)
#undef CONV_LOAD
#undef CONV_MMAC

  // ---- epilogue: FiLM + relu (+ blend + rgb for WHICH=1) ----
  const int y = y0 + wid;
  const float* fg = film + WHICH * 2 * 2048;        // g  [32][64]
  const float* fb = fg + 2048;                      // be [32][64]
  float bs = 0.f, obs = 0.f;
  if (WHICH == 1) { bs = 1.f / (1.f + expf(-blendp[0])); obs = 1.f - bs; }
  unsigned short* drow = dst + (size_t)s * 262144 + y * 4096;
  const unsigned short* grow = (WHICH == 1) ? (gold + (size_t)s * 262144 + y * 4096) : (const unsigned short*)nullptr;

  #pragma unroll
  for (int m = 0; m < 4; ++m) {
    const int co0 = m * 16 + lhi * 4;               // C/D: row(co) = lhi*4 + reg (m89)
    const float4 g  = *(const float4*)&fg[s * 64 + co0];
    const float4 be = *(const float4*)&fb[s * 64 + co0];
    #pragma unroll
    for (int n = 0; n < 4; ++n) {
      const int x = n * 16 + l15;                   // C/D: col(x) = lane&15
      const int off = (x * 128 + co0 * 2) ^ ((x & 7) << 4);
      const f32x4 v = acc[m][n];
      const float u0 = fmaxf(g.x * v[0] + be.x, 0.f);
      const float u1 = fmaxf(g.y * v[1] + be.y, 0.f);
      const float u2 = fmaxf(g.z * v[2] + be.z, 0.f);
      const float u3 = fmaxf(g.w * v[3] + be.w, 0.f);
      if (WHICH == 0) {
        ushort4 pk; pk.x = f2bf(u0); pk.y = f2bf(u1); pk.z = f2bf(u2); pk.w = f2bf(u3);
        *(ushort4*)((char*)drow + off) = pk;
      } else {
        const ushort4 od = *(const ushort4*)((const char*)grow + off);
        const float g0 = obs * bf2f(od.x) + bs * u0;
        const float g1 = obs * bf2f(od.y) + bs * u1;
        const float g2 = obs * bf2f(od.z) + bs * u2;
        const float g3 = obs * bf2f(od.w) + bs * u3;
        ushort4 pk; pk.x = f2bf(g0); pk.y = f2bf(g1); pk.z = f2bf(g2); pk.w = f2bf(g3);
        *(ushort4*)((char*)drow + off) = pk;
        if (co0 == 0) {                             // rgb channels 0..2
          const float r0 = 1.f / (1.f + expf(-g0));
          const float r1 = 1.f / (1.f + expf(-g1));
          const float r2 = 1.f / (1.f + expf(-g2));
          float* ob = out + 393216 + (size_t)((t * 32 + s) * 3) * 4096 + y * 64 + x;
          ob[0] = r0; ob[4096] = r1; ob[8192] = r2;
          if (t == 31) {                            // traj[-1] head copy
            float* o2 = out + (size_t)(s * 3) * 4096 + y * 64 + x;
            o2[0] = r0; o2[4096] = r1; o2[8192] = r2;
          }
        }
      }
    }
  }
}

extern "C" void kernel_launch(void* const* d_in, const int* in_sizes, int n_in,
                              void* d_out, int out_size, void* d_ws, size_t ws_size,
                              hipStream_t stream) {
  (void)in_sizes; (void)n_in; (void)out_size; (void)ws_size;
  const int*   labels = (const int*)d_in[0];
  const float* gin    = (const float*)d_in[1];
  const float* emb    = (const float*)d_in[2];
  const float* hw1    = (const float*)d_in[3];
  const float* hb1    = (const float*)d_in[4];
  const float* hw2    = (const float*)d_in[5];
  const float* hb2    = (const float*)d_in[6];
  const float* hw3    = (const float*)d_in[7];
  const float* hb3    = (const float*)d_in[8];
  const float* f1w1   = (const float*)d_in[9];
  const float* f1b1   = (const float*)d_in[10];
  const float* f1w2   = (const float*)d_in[11];
  const float* f1b2   = (const float*)d_in[12];
  const float* f2w1   = (const float*)d_in[13];
  const float* f2b1   = (const float*)d_in[14];
  const float* f2w2   = (const float*)d_in[15];
  const float* f2b2   = (const float*)d_in[16];
  const float* blend  = (const float*)d_in[17];
  float* out = (float*)d_out;

  char* ws = (char*)d_ws;                               // ~55.1 MB used
  unsigned short* grid0 = (unsigned short*)(ws + (size_t)0);         // 16 MB
  unsigned short* grid1 = (unsigned short*)(ws + (size_t)16777216);  // 16 MB
  unsigned short* ubuf  = (unsigned short*)(ws + (size_t)33554432);  // 16 MB
  unsigned short* Wbuf  = (unsigned short*)(ws + (size_t)50331648);  // 4.72 MB
  float* h2T  = (float*)(ws + (size_t)55050240);                     // 32 KB
  float* film = (float*)(ws + (size_t)55083008);                     // 32 KB

  hyper_kernel<<<32, 256, 0, stream>>>(labels, emb, hw1, hb1, hw2, hb2, h2T);
  film_kernel<<<dim3(32, 2), 128, 0, stream>>>(labels, emb, f1w1, f1b1, f1w2, f1b2,
                                               f2w1, f2b1, f2w2, f2b2, film);
  wgen_kernel<<<1152, 256, 0, stream>>>(h2T, hw3, hb3, Wbuf);
  init_kernel<<<2048, 256, 0, stream>>>(gin, grid0);

  for (int t = 0; t < 32; ++t) {
    unsigned short* gi = (t & 1) ? grid1 : grid0;
    unsigned short* go = (t & 1) ? grid0 : grid1;
    conv_kernel<0><<<256, 512, 0, stream>>>(Wbuf, gi, ubuf, nullptr, film, nullptr, nullptr, t);
    conv_kernel<1><<<256, 512, 0, stream>>>(Wbuf, ubuf, go, gi, film, blend, out, t);
  }
}